// Round 14
// baseline (1129.281 us; speedup 1.0000x reference)
//
#include <hip/hip_runtime.h>
#include <cstdint>
#include <cstddef>

#define B_N 1024
#define V_N 1024
#define F_N 8192
#define NSEL 16
#define NITER 16
#define EPSV 1e-3f
#define WINF 0.008f
#define CANDMAX 64
#define CAND2 256
#define NTILE 64           // F_N / 128 column tiles

#define BM 64
#define BN 128
#define BK 32
#define NBN (F_N / BN)   // fallback path

typedef __attribute__((ext_vector_type(4))) float f32x4;
typedef __attribute__((ext_vector_type(8))) short bf16x8;
typedef unsigned short u16;
typedef unsigned char u8;

#define GLDS16(g, l) __builtin_amdgcn_global_load_lds((__attribute__((address_space(1))) void*)(g), (__attribute__((address_space(3))) void*)(l), 16, 0, 0)

__device__ __forceinline__ u16 f2bf(float f) {
  unsigned u = __float_as_uint(f);
  return (u16)((u + 0x7FFFu + ((u >> 16) & 1u)) >> 16);
}

// ---------------------------------------------------------------------------
// helpers
// ---------------------------------------------------------------------------
__device__ __forceinline__ float block_sum256(float v, float* sbuf) {
#pragma unroll
  for (int o = 32; o > 0; o >>= 1) v += __shfl_down(v, o, 64);
  int lane = threadIdx.x & 63, wid = threadIdx.x >> 6;
  if (lane == 0) sbuf[wid] = v;
  __syncthreads();
  float r = sbuf[0] + sbuf[1] + sbuf[2] + sbuf[3];
  __syncthreads();
  return r;
}

// wave-local sum tree, identical lane order to block_sum256's intra-wave tree
__device__ __forceinline__ float wave_tree64(float v) {
#pragma unroll
  for (int o = 32; o > 0; o >>= 1) v += __shfl_down(v, o, 64);
  return v;
}

// exact sequential dot, bit-identical to round-1's k-ordered FMA accumulation
__device__ __forceinline__ float seq_dot(const float* __restrict__ xrow,
                                         const float* __restrict__ sr) {
  float acc = 0.f;
  for (int k = 0; k < V_N; k += 4) {
    float4 xv = *(const float4*)(xrow + k);
    acc = __builtin_fmaf(xv.x, sr[k + 0], acc);
    acc = __builtin_fmaf(xv.y, sr[k + 1], acc);
    acc = __builtin_fmaf(xv.z, sr[k + 2], acc);
    acc = __builtin_fmaf(xv.w, sr[k + 3], acc);
  }
  return acc;
}

// ---------------------------------------------------------------------------
// total_var pieces (also zeroes act_cnt)
// ---------------------------------------------------------------------------
__global__ __launch_bounds__(256) void rowvar_kernel(const float* __restrict__ y,
                                                     const float* __restrict__ mean_y,
                                                     float* __restrict__ rowvar,
                                                     int* __restrict__ act_cnt) {
  int b = blockIdx.x, t = threadIdx.x;
  __shared__ float sred[4];
  float4 yv = *(const float4*)(y + (size_t)b * V_N + t * 4);
  float4 mv = *(const float4*)(mean_y + t * 4);
  float dx = yv.x - mv.x, dy = yv.y - mv.y, dz = yv.z - mv.z, dw = yv.w - mv.w;
  float p = dx * dx + dy * dy + dz * dz + dw * dw;
  float s = block_sum256(p, sred);
  if (t == 0) { rowvar[b] = s; act_cnt[b] = 0; }
}

__global__ __launch_bounds__(256) void reduce_var_kernel(const float* __restrict__ rowvar,
                                                         float* __restrict__ totvar) {
  __shared__ float sred[4];
  int t = threadIdx.x;
  float p = 0.f;
#pragma unroll
  for (int i = 0; i < 4; i++) p += rowvar[t * 4 + i];
  float s = block_sum256(p, sred);
  if (t == 0) totvar[0] = s / (float)B_N;
}

// ---------------------------------------------------------------------------
// FAST PATH: xs -> bf16, R init (+ qv row scale)
// ---------------------------------------------------------------------------
__global__ __launch_bounds__(256) void xh_kernel(const float* __restrict__ xs,
                                                 u16* __restrict__ Xh) {
  int b = blockIdx.x, t = threadIdx.x;
  float4 v = *(const float4*)(xs + (size_t)b * V_N + t * 4);
  u16* o = Xh + (size_t)b * V_N + t * 4;
  o[0] = f2bf(v.x); o[1] = f2bf(v.y); o[2] = f2bf(v.z); o[3] = f2bf(v.w);
}

__global__ __launch_bounds__(256) void init_kernel(const float* __restrict__ x,
                                                   float* __restrict__ R,
                                                   u16* __restrict__ Rh,
                                                   float* __restrict__ rn2,
                                                   float* __restrict__ qv) {
  int b = blockIdx.x, t = threadIdx.x;
  __shared__ float sred[4];
  float4 v = *(const float4*)(x + (size_t)b * V_N + t * 4);
  *(float4*)(R + (size_t)b * V_N + t * 4) = v;
  u16* o = Rh + (size_t)b * V_N + t * 4;
  o[0] = f2bf(v.x); o[1] = f2bf(v.y); o[2] = f2bf(v.z); o[3] = f2bf(v.w);
  float p = v.x * v.x + v.y * v.y + v.z * v.z + v.w * v.w;
  float s = block_sum256(p, sred);
  if (t == 0) {
    rn2[b] = s;
    qv[b] = 250.0f / fmaxf(WINF * sqrtf(s), 1e-20f);
  }
}

// ---------------------------------------------------------------------------
// FAST PATH: bf16 MFMA GEMM, 2-phase double-buffered staging (round-13).
// Epilogue: per-(row,tile) max + packed u8 quantized distance.
// ---------------------------------------------------------------------------
__global__ __launch_bounds__(256) void gemm_scan_kernel(const u16* __restrict__ Rh,
                                                        const u16* __restrict__ Xh,
                                                        const float* __restrict__ qv,
                                                        u8* __restrict__ inner8,
                                                        float* __restrict__ pval) {
  __shared__ u16 As[2][128 * 32];
  __shared__ u16 Bs[2][128 * 32];
  __shared__ float srmax[128][2];
  const int tid = threadIdx.x;
  const int w = tid >> 6, l = tid & 63;
  const int bn = blockIdx.x, bm = blockIdx.y;
  const int wr = w >> 1, wc = w & 1;
  const int lr = l & 15, lg = l >> 4;

  f32x4 acc[4][4];
#pragma unroll
  for (int m = 0; m < 4; m++)
#pragma unroll
    for (int n = 0; n < 4; n++) acc[m][n] = (f32x4){0.f, 0.f, 0.f, 0.f};

  const u16* Ab = Rh + (size_t)bm * 128 * V_N;
  const u16* Bb = Xh + (size_t)bn * 128 * V_N;
  const int srow = w * 16 + (l >> 2);
  const int scol = (l & 3) * 8;

  // prologue: stage K-tile 0 into buffer 0
#pragma unroll
  for (int i = 0; i < 2; i++) {
    GLDS16(Ab + (size_t)(i * 64 + srow) * V_N + 0 + scol, &As[0][i * 2048 + w * 512]);
    GLDS16(Bb + (size_t)(i * 64 + srow) * V_N + 0 + scol, &Bs[0][i * 2048 + w * 512]);
  }
  __syncthreads();

  int cur = 0;
  for (int k0 = 0; k0 < V_N; k0 += 32) {
    int nxt = cur ^ 1;
    if (k0 + 32 < V_N) {
#pragma unroll
      for (int i = 0; i < 2; i++) {
        GLDS16(Ab + (size_t)(i * 64 + srow) * V_N + k0 + 32 + scol, &As[nxt][i * 2048 + w * 512]);
        GLDS16(Bb + (size_t)(i * 64 + srow) * V_N + k0 + 32 + scol, &Bs[nxt][i * 2048 + w * 512]);
      }
    }
    bf16x8 af[4], bfr[4];
#pragma unroll
    for (int m = 0; m < 4; m++) af[m] = *(const bf16x8*)&As[cur][(wr * 64 + m * 16 + lr) * 32 + lg * 8];
#pragma unroll
    for (int n = 0; n < 4; n++) bfr[n] = *(const bf16x8*)&Bs[cur][(wc * 64 + n * 16 + lr) * 32 + lg * 8];
#pragma unroll
    for (int m = 0; m < 4; m++)
#pragma unroll
      for (int n = 0; n < 4; n++)
        acc[m][n] = __builtin_amdgcn_mfma_f32_16x16x32_bf16(af[m], bfr[n], acc[m][n], 0, 0, 0);
    __syncthreads();   // drains vmcnt (next buffer staged) + all waves done with cur
    cur = nxt;
  }

  // phase 1: per-(row, 64-col-half) maxes into LDS
#pragma unroll
  for (int m = 0; m < 4; m++) {
#pragma unroll
    for (int j = 0; j < 4; j++) {
      float pm = acc[m][0][j];
#pragma unroll
      for (int n = 1; n < 4; n++) pm = fmaxf(pm, acc[m][n][j]);
#pragma unroll
      for (int mk = 1; mk < 16; mk <<= 1) pm = fmaxf(pm, __shfl_xor(pm, mk, 64));
      if (lr == 0) srmax[wr * 64 + m * 16 + lg * 4 + j][wc] = pm;
    }
  }
  __syncthreads();
  // pval write
  if (tid < 128) {
    float v = fmaxf(srmax[tid][0], srmax[tid][1]);
    pval[(size_t)(bm * 128 + tid) * NTILE + bn] = v;
  }
  // phase 2: packed u8 quantized distance (one u32 store per (m,j))
#pragma unroll
  for (int m = 0; m < 4; m++) {
#pragma unroll
    for (int j = 0; j < 4; j++) {
      int row = wr * 64 + m * 16 + lg * 4 + j;
      int gm = bm * 128 + row;
      float rmax = fmaxf(srmax[row][0], srmax[row][1]);
      float qinv = qv[gm];
      unsigned pack = 0;
#pragma unroll
      for (int n = 0; n < 4; n++) {
        float df = floorf((rmax - acc[m][n][j]) * qinv);
        unsigned u = df >= 254.f ? 254u : (unsigned)(int)df;
        pack |= u << (8 * n);
      }
      *(unsigned*)(inner8 + (size_t)gm * F_N + bn * 128 + wc * 64 + lr * 4) = pack;
    }
  }
}

// ---------------------------------------------------------------------------
// FAST PATH v14: full wave-role split. Wave 0 privately runs threshold ->
// ballot candidate collect -> exact rescore (shuffle argmax) -> merge ->
// new-atom g, all CONCURRENT with waves 1-3's paired g-phase. One join
// barrier. Overflow tiers preserved post-join. All selection/update
// arithmetic identical to passing round-13 kernel.
// ---------------------------------------------------------------------------
__global__ __launch_bounds__(256, 4) void scan_update_kernel(const float* __restrict__ x,
                                                             const float* __restrict__ xs,
                                                             const u8* __restrict__ inner8,
                                                             const float* __restrict__ pval,
                                                             float* __restrict__ rn2,
                                                             float* __restrict__ qv,
                                                             int* __restrict__ act_ids,
                                                             float* __restrict__ act_w,
                                                             int* __restrict__ act_cnt,
                                                             float* __restrict__ R,
                                                             u16* __restrict__ Rh) {
  int b = blockIdx.x, t = threadIdx.x;
  const int lane = t & 63, wid = t >> 6;
  __shared__ float sr[V_N];
  __shared__ float spv[NTILE];
  __shared__ float sred[4];
  __shared__ float scsqp[4], scrp[4];
  __shared__ int   scand[CAND2];
  __shared__ float scval[CAND2];
  __shared__ float sfv[256];
  __shared__ int   sfi[256];
  __shared__ int   stotal;
  __shared__ int   sbii;
  __shared__ float sg[NSEL + 2];
  __shared__ float sw[NSEL + 2];
  __shared__ int   sids[NSEL + 2];
  __shared__ int   ssel[NSEL + 2];
  __shared__ int   scnt, scnt0, sjnew;

  // ---- stage 1: residual row, x row, tile maxes, active set -> LDS
  float4 rv = *(const float4*)(R + (size_t)b * V_N + t * 4);
  float4 xrow = *(const float4*)(x + (size_t)b * V_N + t * 4);
  *(float4*)&sr[t * 4] = rv;
  if (t < NTILE) spv[t] = pval[(size_t)b * NTILE + t];
  if (t == 0) {
    int c0 = act_cnt[b]; scnt0 = c0;
    for (int j = 0; j < c0; j++) { sids[j] = act_ids[b * NSEL + j]; sw[j] = act_w[b * NSEL + j]; }
  }
  __syncthreads();
  int cnt0 = scnt0;

  // ---- stage 2: CONCURRENT {waves 1-3: paired g} | {wave 0: full select}
  if (wid >= 1) {
#pragma unroll
    for (int bb = 0; bb < 3; bb++) {
      int j0 = (wid - 1) + 3 * (2 * bb);
      int j1 = (wid - 1) + 3 * (2 * bb + 1);
      bool v0 = (j0 < cnt0) && (sw[j0] != 0.f);   // wave-uniform (LDS)
      bool v1 = (j1 < cnt0) && (sw[j1] != 0.f);
      const float* xr0 = xs + (size_t)sids[v0 ? j0 : 0] * V_N;
      const float* xr1 = xs + (size_t)sids[v1 ? j1 : 0] * V_N;
      float4 a0[4], a1[4];
#pragma unroll
      for (int vw = 0; vw < 4; vw++) {
        int vt = vw * 64 + lane;
        if (v0) a0[vw] = *(const float4*)(xr0 + vt * 4);
        if (v1) a1[vw] = *(const float4*)(xr1 + vt * 4);
      }
      if (v0) {
        float part[4];
#pragma unroll
        for (int vw = 0; vw < 4; vw++) {
          int vt = vw * 64 + lane;
          float4 rl4 = *(const float4*)&sr[vt * 4];
          float p = a0[vw].x * rl4.x + a0[vw].y * rl4.y + a0[vw].z * rl4.z + a0[vw].w * rl4.w;
          part[vw] = wave_tree64(p);
        }
        if (lane == 0) sg[j0] = part[0] + part[1] + part[2] + part[3];
      }
      if (v1) {
        float part[4];
#pragma unroll
        for (int vw = 0; vw < 4; vw++) {
          int vt = vw * 64 + lane;
          float4 rl4 = *(const float4*)&sr[vt * 4];
          float p = a1[vw].x * rl4.x + a1[vw].y * rl4.y + a1[vw].z * rl4.z + a1[vw].w * rl4.w;
          part[vw] = wave_tree64(p);
        }
        if (lane == 0) sg[j1] = part[0] + part[1] + part[2] + part[3];
      }
    }
  } else {
    // ---- wave 0: threshold (butterfly max, exact) ----
    float pv = spv[lane];                 // NTILE == 64 == wave width
#pragma unroll
    for (int o = 32; o > 0; o >>= 1) pv = fmaxf(pv, __shfl_xor(pv, o, 64));
    float M = pv;
    float win = WINF * sqrtf(rn2[b]);
    float thr = M - win;
    float qinv = 250.0f / fmaxf(win, 1e-20f);   // same expression as qv producer

    // ---- candidate collect via ballot compaction (no atomics) ----
    const u8* irow8 = inner8 + (size_t)b * F_N;
    int totalc = 0;
    for (int tt = 0; tt < NTILE; tt++) {
      float pvt = spv[tt];               // broadcast read, wave-uniform
      if (pvt >= thr) {
        int lim = (int)floorf((pvt - thr) * qinv);
#pragma unroll
        for (int half = 0; half < 2; half++) {
          int p = half * 64 + lane;
          int u8v = irow8[tt * 128 + p];
          bool pred = (u8v <= lim);
          unsigned long long mask = __ballot(pred);
          if (pred) {
            int pos = totalc + (int)__popcll(mask & ((1ull << lane) - 1ull));
            if (pos < CAND2) {
              int col = (p & 64) + (p & 3) * 16 + ((p >> 2) & 15);   // un-permute
              scand[pos] = tt * 128 + col;
            }
          }
          totalc += (int)__popcll(mask);
        }
      }
    }
    if (lane == 0) stotal = totalc;

    if (totalc <= CANDMAX) {
      asm volatile("s_waitcnt lgkmcnt(0)" ::: "memory");   // scand RAW within wave
      int nc = totalc;
      float bv = -1e30f; int bi = 0x7fffffff;
      if (lane < nc) { bi = scand[lane]; bv = seq_dot(xs + (size_t)bi * V_N, sr); }
      // shuffle argmax (max with lowest-index tiebreak: order-independent exact)
#pragma unroll
      for (int o = 32; o > 0; o >>= 1) {
        float ov = __shfl_xor(bv, o, 64);
        int   oi = __shfl_xor(bi, o, 64);
        if (ov > bv || (ov == bv && oi < bi)) { bv = ov; bi = oi; }
      }
      // all wave-0 lanes hold winner bi
      int jnewLocal = -1;
      if (lane == 0) {
        int cnt = cnt0;
        int pos = -1;
        for (int j = 0; j < cnt; j++) if (sids[j] == bi) pos = j;
        if (pos < 0) { pos = cnt; sids[cnt] = bi; sw[cnt] = 0.f; cnt++; }
        for (int j = 0; j < cnt; j++) ssel[j] = (sw[j] != 0.f) || (j == pos) ? 1 : 0;
        for (int j = 0; j < cnt; j++) if (!ssel[j]) sg[j] = 0.f;
        jnewLocal = (sw[pos] == 0.f) ? pos : -1;
        scnt = cnt;
      }
      int jnew = __shfl(jnewLocal, 0, 64);
      if (jnew >= 0) {
        const float* xr0 = xs + (size_t)bi * V_N;
        float part[4];
#pragma unroll
        for (int vw = 0; vw < 4; vw++) {
          int vt = vw * 64 + lane;
          float4 xvv = *(const float4*)(xr0 + vt * 4);
          float4 rl4 = *(const float4*)&sr[vt * 4];
          float p = xvv.x * rl4.x + xvv.y * rl4.y + xvv.z * rl4.z + xvv.w * rl4.w;
          part[vw] = wave_tree64(p);
        }
        if (lane == 0) sg[jnew] = part[0] + part[1] + part[2] + part[3];
      }
    }
  }
  __syncthreads();   // join: selection + g published

  // ---- overflow tiers (rare): all threads ----
  int total = stotal;
  if (total > CANDMAX) {
    if (total <= CAND2) {
      if (t < total) scval[t] = seq_dot(xs + (size_t)scand[t] * V_N, sr);
      __syncthreads();
      if (t == 0) {
        float bv = scval[0]; int bi2 = scand[0];
        for (int c = 1; c < total; c++) {
          float v = scval[c]; int id = scand[c];
          if (v > bv || (v == bv && id < bi2)) { bv = v; bi2 = id; }
        }
        sbii = bi2;
      }
      __syncthreads();
    } else {
      float bv = -1e30f; int bi2 = 0x7fffffff;
      for (int f = t; f < F_N; f += 256) {
        float acc = seq_dot(xs + (size_t)f * V_N, sr);
        if (acc > bv) { bv = acc; bi2 = f; }
      }
      sfv[t] = bv; sfi[t] = bi2;
      __syncthreads();
      if (t == 0) {
        float bbv = sfv[0]; int bbi = sfi[0];
        for (int c = 1; c < 256; c++) {
          float v = sfv[c]; int id = sfi[c];
          if (v > bbv || (v == bbv && id < bbi)) { bbv = v; bbi = id; }
        }
        sbii = bbi;
      }
      __syncthreads();
    }
    if (t == 0) {
      int bi = sbii;
      int cnt = cnt0;
      int pos = -1;
      for (int j = 0; j < cnt; j++) if (sids[j] == bi) pos = j;
      if (pos < 0) { pos = cnt; sids[cnt] = bi; sw[cnt] = 0.f; cnt++; }
      for (int j = 0; j < cnt; j++) ssel[j] = (sw[j] != 0.f) || (j == pos) ? 1 : 0;
      for (int j = 0; j < cnt; j++) if (!ssel[j]) sg[j] = 0.f;
      sjnew = (sw[pos] == 0.f) ? pos : -1;
      scnt = cnt;
    }
    __syncthreads();
    int jnew = sjnew;
    if (jnew >= 0 && wid == 0) {
      const float* xr0 = xs + (size_t)sids[jnew] * V_N;
      float part[4];
#pragma unroll
      for (int vw = 0; vw < 4; vw++) {
        int vt = vw * 64 + lane;
        float4 xvv = *(const float4*)(xr0 + vt * 4);
        float4 rl4 = *(const float4*)&sr[vt * 4];
        float p = xvv.x * rl4.x + xvv.y * rl4.y + xvv.z * rl4.z + xvv.w * rl4.w;
        part[vw] = wave_tree64(p);
      }
      if (lane == 0) sg[jnew] = part[0] + part[1] + part[2] + part[3];
    }
    __syncthreads();
  }

  int cnt = scnt;

  // ---- batched register prefetch of all selected rows
  float4 rl = *(const float4*)&sr[t * 4];
  float4 xv[NSEL + 1];
#pragma unroll
  for (int j = 0; j < NSEL + 1; j++) {
    int jj = j < cnt ? j : 0;
    xv[j] = *(const float4*)(xs + (size_t)sids[jj] * V_N + t * 4);
  }

  // ---- c = sum_j g_j D_j (from registers, ascending j)
  float4 cv = {0.f, 0.f, 0.f, 0.f};
#pragma unroll
  for (int j = 0; j < NSEL + 1; j++) {
    if (j < cnt) {
      if (ssel[j]) {   // uniform (LDS)
        float g = sg[j];
        cv.x += g * xv[j].x; cv.y += g * xv[j].y; cv.z += g * xv[j].z; cv.w += g * xv[j].w;
      }
    }
  }
  float pcsq = cv.x * cv.x + cv.y * cv.y + cv.z * cv.z + cv.w * cv.w;
  float pcr  = cv.x * rl.x + cv.y * rl.y + cv.z * rl.z + cv.w * rl.w;
  {
    // fused csq/cr: wave trees + single barrier + same 4-term L2R combine
    float s1 = wave_tree64(pcsq);
    float s2 = wave_tree64(pcr);
    if (lane == 0) { scsqp[wid] = s1; scrp[wid] = s2; }
  }
  __syncthreads();

  if (t == 0) {
    float csq = scsqp[0] + scsqp[1] + scsqp[2] + scsqp[3];
    float cr  = scrp[0] + scrp[1] + scrp[2] + scrp[3];
    float step = cr / fmaxf(csq, EPSV);
    for (int j = 0; j < cnt; j++)
      if (ssel[j]) sw[j] = fmaxf(sw[j] + step * sg[j], 0.f);
    for (int j = 0; j < cnt; j++) {
      act_ids[b * NSEL + j] = sids[j];
      act_w[b * NSEL + j] = sw[j];
    }
    act_cnt[b] = cnt;
  }
  __syncthreads();

  // ---- new residual from cached rows (ascending j); R/Rh/rn2/qv
  float4 r = xrow;
#pragma unroll
  for (int j = 0; j < NSEL + 1; j++) {
    if (j < cnt) {
      float wv = sw[j];
      if (wv != 0.f) {   // uniform (LDS); w!=0 => selected => xv[j] valid
        r.x -= wv * xv[j].x; r.y -= wv * xv[j].y; r.z -= wv * xv[j].z; r.w -= wv * xv[j].w;
      }
    }
  }
  *(float4*)(R + (size_t)b * V_N + t * 4) = r;
  u16* o = Rh + (size_t)b * V_N + t * 4;
  o[0] = f2bf(r.x); o[1] = f2bf(r.y); o[2] = f2bf(r.z); o[3] = f2bf(r.w);
  float p2 = r.x * r.x + r.y * r.y + r.z * r.z + r.w * r.w;
  {
    // fused rn2: wave trees + single barrier + same 4-term L2R combine
    float s1 = wave_tree64(p2);
    if (lane == 0) scsqp[wid] = s1;
  }
  __syncthreads();
  if (t == 0) {
    float s2 = scsqp[0] + scsqp[1] + scsqp[2] + scsqp[3];
    rn2[b] = s2;
    qv[b] = 250.0f / fmaxf(WINF * sqrtf(s2), 1e-20f);
  }
}

// ---------------------------------------------------------------------------
// FALLBACK PATH (round-1 fp32 pipeline, used only if ws_size is too small)
// ---------------------------------------------------------------------------
__global__ __launch_bounds__(256) void residual_kernel(const float* __restrict__ x,
                                                       const float* __restrict__ xs,
                                                       const int* __restrict__ act_ids,
                                                       const float* __restrict__ act_w,
                                                       const int* __restrict__ act_cnt,
                                                       float* __restrict__ R) {
  int b = blockIdx.x, t = threadIdx.x;
  float4 r = *(const float4*)(x + (size_t)b * V_N + t * 4);
  int cnt = act_cnt[b];
  for (int j = 0; j < cnt; j++) {
    float w = act_w[b * NSEL + j];
    if (w != 0.f) {
      const float* xr = xs + (size_t)act_ids[b * NSEL + j] * V_N;
      float4 xv = *(const float4*)(xr + t * 4);
      r.x -= w * xv.x; r.y -= w * xv.y; r.z -= w * xv.z; r.w -= w * xv.w;
    }
  }
  *(float4*)(R + (size_t)b * V_N + t * 4) = r;
}

__global__ __launch_bounds__(256) void gemm_argmax_kernel(const float* __restrict__ R,
                                                          const float* __restrict__ xs,
                                                          float* __restrict__ pval,
                                                          int* __restrict__ pidx) {
  __shared__ float sA[BK * 68];
  __shared__ float sB[BK * 132];
  __shared__ float sMv[64 * 33];
  __shared__ int   sMi[64 * 33];

  int tid = threadIdx.x;
  int bn = blockIdx.x, bm = blockIdx.y;
  float acc[8][4];
#pragma unroll
  for (int i = 0; i < 8; i++)
#pragma unroll
    for (int j = 0; j < 4; j++) acc[i][j] = 0.f;

  int r0 = (tid >> 5) << 3;
  int n0 = (tid & 31) << 2;
  const float* Rbase = R + (size_t)(bm * BM) * V_N;
  const float* Xbase = xs + (size_t)(bn * BN) * V_N;

  for (int k0 = 0; k0 < V_N; k0 += BK) {
    {
      int m = tid >> 2, kf = (tid & 3) * 4;
      float4 v = *(const float4*)(Rbase + (size_t)m * V_N + k0 + kf);
      sA[(kf + 0) * 68 + m] = v.x; sA[(kf + 1) * 68 + m] = v.y;
      sA[(kf + 2) * 68 + m] = v.z; sA[(kf + 3) * 68 + m] = v.w;
      float4 v2 = *(const float4*)(Rbase + (size_t)m * V_N + k0 + kf + 16);
      sA[(kf + 16) * 68 + m] = v2.x; sA[(kf + 17) * 68 + m] = v2.y;
      sA[(kf + 18) * 68 + m] = v2.z; sA[(kf + 19) * 68 + m] = v2.w;
    }
    {
      int nn = tid >> 3, kf = (tid & 7) * 4;
#pragma unroll
      for (int i = 0; i < 4; i++) {
        int n = nn + i * 32;
        float4 v = *(const float4*)(Xbase + (size_t)n * V_N + k0 + kf);
        sB[(kf + 0) * 132 + n] = v.x; sB[(kf + 1) * 132 + n] = v.y;
        sB[(kf + 2) * 132 + n] = v.z; sB[(kf + 3) * 132 + n] = v.w;
      }
    }
    __syncthreads();
#pragma unroll
    for (int k = 0; k < BK; k++) {
      float4 aL = *(float4*)&sA[k * 68 + r0];
      float4 aH = *(float4*)&sA[k * 68 + r0 + 4];
      float4 bv = *(float4*)&sB[k * 132 + n0];
      float a[8] = {aL.x, aL.y, aL.z, aL.w, aH.x, aH.y, aH.z, aH.w};
      float bb[4] = {bv.x, bv.y, bv.z, bv.w};
#pragma unroll
      for (int i = 0; i < 8; i++)
#pragma unroll
        for (int j = 0; j < 4; j++) acc[i][j] += a[i] * bb[j];
    }
    __syncthreads();
  }

#pragma unroll
  for (int i = 0; i < 8; i++) {
    float bvv = acc[i][0]; int bj = 0;
#pragma unroll
    for (int j = 1; j < 4; j++)
      if (acc[i][j] > bvv) { bvv = acc[i][j]; bj = j; }
    sMv[(r0 + i) * 33 + (tid & 31)] = bvv;
    sMi[(r0 + i) * 33 + (tid & 31)] = bn * BN + n0 + bj;
  }
  __syncthreads();
  if (tid < 64) {
    float bvv = sMv[tid * 33]; int bi = sMi[tid * 33];
    for (int c = 1; c < 32; c++) {
      float v = sMv[tid * 33 + c];
      if (v > bvv) { bvv = v; bi = sMi[tid * 33 + c]; }
    }
    pval[(size_t)(bm * BM + tid) * NBN + bn] = bvv;
    pidx[(size_t)(bm * BM + tid) * NBN + bn] = bi;
  }
}

__global__ __launch_bounds__(256) void combine_update_kernel(const float* __restrict__ R,
                                                             const float* __restrict__ xs,
                                                             const float* __restrict__ pval,
                                                             const int* __restrict__ pidx,
                                                             int* __restrict__ act_ids,
                                                             float* __restrict__ act_w,
                                                             int* __restrict__ act_cnt) {
  int b = blockIdx.x, t = threadIdx.x;
  __shared__ float sr[V_N];
  __shared__ float sred[4];
  __shared__ float sg[NSEL + 1];
  __shared__ float sw[NSEL + 1];
  __shared__ int   sids[NSEL + 1];
  __shared__ int   ssel[NSEL + 1];
  __shared__ int   scnt;

  float4 rv = *(const float4*)(R + (size_t)b * V_N + t * 4);
  *(float4*)&sr[t * 4] = rv;

  if (t == 0) {
    const float* pv = pval + (size_t)b * NBN;
    const int* pi = pidx + (size_t)b * NBN;
    float bv = pv[0]; int bi = pi[0];
    for (int c = 1; c < NBN; c++) {
      float v = pv[c];
      if (v > bv) { bv = v; bi = pi[c]; }
    }
    int cnt = act_cnt[b];
    for (int j = 0; j < cnt; j++) { sids[j] = act_ids[b * NSEL + j]; sw[j] = act_w[b * NSEL + j]; }
    int pos = -1;
    for (int j = 0; j < cnt; j++) if (sids[j] == bi) pos = j;
    if (pos < 0) { pos = cnt; sids[cnt] = bi; sw[cnt] = 0.f; cnt++; }
    for (int j = 0; j < cnt; j++) ssel[j] = (sw[j] != 0.f) || (j == pos) ? 1 : 0;
    scnt = cnt;
  }
  __syncthreads();
  int cnt = scnt;

  for (int j = 0; j < cnt; j++) {
    if (!ssel[j]) { if (t == 0) sg[j] = 0.f; continue; }
    const float* xr = xs + (size_t)sids[j] * V_N;
    float4 xv = *(const float4*)(xr + t * 4);
    float4 rl = *(const float4*)&sr[t * 4];
    float p = xv.x * rl.x + xv.y * rl.y + xv.z * rl.z + xv.w * rl.w;
    float s = block_sum256(p, sred);
    if (t == 0) sg[j] = s;
  }
  __syncthreads();

  float4 cv = {0.f, 0.f, 0.f, 0.f};
  for (int j = 0; j < cnt; j++) {
    if (ssel[j]) {
      float g = sg[j];
      const float* xr = xs + (size_t)sids[j] * V_N;
      float4 xv = *(const float4*)(xr + t * 4);
      cv.x += g * xv.x; cv.y += g * xv.y; cv.z += g * xv.z; cv.w += g * xv.w;
    }
  }
  float4 rl = *(const float4*)&sr[t * 4];
  float pcsq = cv.x * cv.x + cv.y * cv.y + cv.z * cv.z + cv.w * cv.w;
  float pcr  = cv.x * rl.x + cv.y * rl.y + cv.z * rl.z + cv.w * rl.w;
  float csq = block_sum256(pcsq, sred);
  float cr  = block_sum256(pcr, sred);

  if (t == 0) {
    float step = cr / fmaxf(csq, EPSV);
    for (int j = 0; j < cnt; j++)
      if (ssel[j]) sw[j] = fmaxf(sw[j] + step * sg[j], 0.f);
    for (int j = 0; j < cnt; j++) {
      act_ids[b * NSEL + j] = sids[j];
      act_w[b * NSEL + j] = sw[j];
    }
    act_cnt[b] = cnt;
  }
}

// ---------------------------------------------------------------------------
// top-k + decode (shared by both paths)
// ---------------------------------------------------------------------------
__global__ __launch_bounds__(256) void topk_kernel(const int* __restrict__ act_ids,
                                                   const float* __restrict__ act_w,
                                                   const int* __restrict__ act_cnt,
                                                   float* __restrict__ out_w,
                                                   float* __restrict__ out_i) {
  int b = blockIdx.x * blockDim.x + threadIdx.x;
  if (b >= B_N) return;
  int cnt = act_cnt[b];
  int ids[NSEL]; float w[NSEL]; int m = 0;
  for (int j = 0; j < cnt; j++) {
    float wv = act_w[b * NSEL + j];
    if (wv > 0.f) { ids[m] = act_ids[b * NSEL + j]; w[m] = wv; m++; }
  }
  for (int i = 1; i < m; i++) {
    float wv = w[i]; int id = ids[i]; int j = i - 1;
    while (j >= 0 && (w[j] < wv || (w[j] == wv && ids[j] > id))) {
      w[j + 1] = w[j]; ids[j + 1] = ids[j]; j--;
    }
    w[j + 1] = wv; ids[j + 1] = id;
  }
  int nf = 0;
  for (int s = m; s < NSEL; s++) {
    for (;;) {
      bool used = false;
      for (int j = 0; j < m; j++) if (ids[j] == nf) used = true;
      if (!used) break;
      nf++;
    }
    ids[s] = nf; w[s] = 0.f; nf++;
  }
  for (int s = 0; s < NSEL; s++) {
    out_w[b * NSEL + s] = w[s];
    out_i[b * NSEL + s] = (float)ids[s];
  }
}

__global__ __launch_bounds__(256) void decode_kernel(const float* __restrict__ y,
                                                     const float* __restrict__ xs,
                                                     const float* __restrict__ ys,
                                                     const float* __restrict__ out_w,
                                                     const float* __restrict__ out_i,
                                                     const float* __restrict__ totvar,
                                                     float* __restrict__ x_rec,
                                                     float* __restrict__ y_rec,
                                                     float* __restrict__ losses) {
  int b = blockIdx.x, t = threadIdx.x;
  __shared__ float swv[NSEL];
  __shared__ int sid[NSEL];
  __shared__ float sred[4];
  if (t < NSEL) { swv[t] = out_w[b * NSEL + t]; sid[t] = (int)out_i[b * NSEL + t]; }
  __syncthreads();
  float4 xr = {0.f, 0.f, 0.f, 0.f}, yr = {0.f, 0.f, 0.f, 0.f};
  for (int s = 0; s < NSEL; s++) {
    float wv = swv[s];
    if (wv != 0.f) {
      const float* xrow = xs + (size_t)sid[s] * V_N;
      const float* yrow = ys + (size_t)sid[s] * V_N;
      float4 a = *(const float4*)(xrow + t * 4);
      float4 c = *(const float4*)(yrow + t * 4);
      xr.x += wv * a.x; xr.y += wv * a.y; xr.z += wv * a.z; xr.w += wv * a.w;
      yr.x += wv * c.x; yr.y += wv * c.y; yr.z += wv * c.z; yr.w += wv * c.w;
    }
  }
  *(float4*)(x_rec + (size_t)b * V_N + t * 4) = xr;
  *(float4*)(y_rec + (size_t)b * V_N + t * 4) = yr;
  float4 yv = *(const float4*)(y + (size_t)b * V_N + t * 4);
  float dx = yv.x - yr.x, dy = yv.y - yr.y, dz = yv.z - yr.z, dw = yv.w - yr.w;
  float p = dx * dx + dy * dy + dz * dz + dw * dw;
  float l2 = block_sum256(p, sred);
  if (t == 0) losses[b] = l2 / totvar[0];
}

// ---------------------------------------------------------------------------
// launch
// ---------------------------------------------------------------------------
extern "C" void kernel_launch(void* const* d_in, const int* in_sizes, int n_in,
                              void* d_out, int out_size, void* d_ws, size_t ws_size,
                              hipStream_t stream) {
  const float* x      = (const float*)d_in[0];
  const float* y      = (const float*)d_in[1];
  const float* xs     = (const float*)d_in[2];
  const float* ys     = (const float*)d_in[3];
  const float* mean_y = (const float*)d_in[4];
  (void)in_sizes; (void)n_in; (void)out_size;

  float* out    = (float*)d_out;
  float* out_w  = out;
  float* out_i  = out + 16384;
  float* out_xr = out + 32768;
  float* out_yr = out + 32768 + 1048576;
  float* out_ls = out + 32768 + 2097152;

  float* ws = (float*)d_ws;

  const size_t FAST_NEED = (size_t)14258177 * 4;

  if (ws_size >= FAST_NEED) {
    float* R      = ws;
    u8*    inner8 = (u8*)(ws + 1048576);      // 8.39 MB
    u16*   Rh     = (u16*)(ws + 5242880);
    u16*   Xh     = (u16*)(ws + 5767168);
    float* rn2    = ws + 9961472;
    int*   aid    = (int*)(ws + 9962496);
    float* aw     = ws + 9978880;
    int*   acn    = (int*)(ws + 9995264);
    float* rv     = ws + 9996288;
    float* tv     = ws + 9997312;
    float* pval   = ws + 14191617;
    float* qv     = ws + 14257153;

    rowvar_kernel<<<B_N, 256, 0, stream>>>(y, mean_y, rv, acn);
    reduce_var_kernel<<<1, 256, 0, stream>>>(rv, tv);
    xh_kernel<<<F_N, 256, 0, stream>>>(xs, Xh);
    init_kernel<<<B_N, 256, 0, stream>>>(x, R, Rh, rn2, qv);

    for (int it = 0; it < NITER; it++) {
      gemm_scan_kernel<<<dim3(F_N / 128, B_N / 128), 256, 0, stream>>>(Rh, Xh, qv, inner8, pval);
      scan_update_kernel<<<B_N, 256, 0, stream>>>(x, xs, inner8, pval, rn2, qv, aid, aw, acn, R, Rh);
    }

    topk_kernel<<<(B_N + 255) / 256, 256, 0, stream>>>(aid, aw, acn, out_w, out_i);
    decode_kernel<<<B_N, 256, 0, stream>>>(y, xs, ys, out_w, out_i, tv, out_xr, out_yr, out_ls);
  } else {
    float* R    = ws;
    float* pval = ws + 1048576;
    int*   pidx = (int*)(ws + 1114112);
    int*   aid  = (int*)(ws + 1179648);
    float* aw   = ws + 1196032;
    int*   acn  = (int*)(ws + 1212416);
    float* rv   = ws + 1213440;
    float* tv   = ws + 1214464;

    rowvar_kernel<<<B_N, 256, 0, stream>>>(y, mean_y, rv, acn);
    reduce_var_kernel<<<1, 256, 0, stream>>>(rv, tv);

    for (int it = 0; it < NITER; it++) {
      residual_kernel<<<B_N, 256, 0, stream>>>(x, xs, aid, aw, acn, R);
      gemm_argmax_kernel<<<dim3(NBN, B_N / BM), 256, 0, stream>>>(R, xs, pval, pidx);
      combine_update_kernel<<<B_N, 256, 0, stream>>>(R, xs, pval, pidx, aid, aw, acn);
    }

    topk_kernel<<<(B_N + 255) / 256, 256, 0, stream>>>(aid, aw, acn, out_w, out_i);
    decode_kernel<<<B_N, 256, 0, stream>>>(y, xs, ys, out_w, out_i, tv, out_xr, out_yr, out_ls);
  }
}

// Round 15
// 981.950 us; speedup vs baseline: 1.1500x; 1.1500x over previous
//
#include <hip/hip_runtime.h>
#include <cstdint>
#include <cstddef>

#define B_N 1024
#define V_N 1024
#define F_N 8192
#define NSEL 16
#define NITER 16
#define EPSV 1e-3f
#define WINF 0.008f
#define CANDMAX 64
#define CAND2 256
#define NTILE 64           // F_N / 128 column tiles

#define BM 64
#define BN 128
#define BK 32
#define NBN (F_N / BN)   // fallback path

typedef __attribute__((ext_vector_type(4))) float f32x4;
typedef __attribute__((ext_vector_type(8))) short bf16x8;
typedef unsigned short u16;
typedef unsigned char u8;

#define GLDS16(g, l) __builtin_amdgcn_global_load_lds((__attribute__((address_space(1))) void*)(g), (__attribute__((address_space(3))) void*)(l), 16, 0, 0)

__device__ __forceinline__ u16 f2bf(float f) {
  unsigned u = __float_as_uint(f);
  return (u16)((u + 0x7FFFu + ((u >> 16) & 1u)) >> 16);
}

// ---------------------------------------------------------------------------
// helpers
// ---------------------------------------------------------------------------
__device__ __forceinline__ float block_sum256(float v, float* sbuf) {
#pragma unroll
  for (int o = 32; o > 0; o >>= 1) v += __shfl_down(v, o, 64);
  int lane = threadIdx.x & 63, wid = threadIdx.x >> 6;
  if (lane == 0) sbuf[wid] = v;
  __syncthreads();
  float r = sbuf[0] + sbuf[1] + sbuf[2] + sbuf[3];
  __syncthreads();
  return r;
}

__device__ __forceinline__ float block_max256(float v, float* sbuf) {
#pragma unroll
  for (int o = 32; o > 0; o >>= 1) v = fmaxf(v, __shfl_down(v, o, 64));
  int lane = threadIdx.x & 63, wid = threadIdx.x >> 6;
  if (lane == 0) sbuf[wid] = v;
  __syncthreads();
  float r = fmaxf(fmaxf(sbuf[0], sbuf[1]), fmaxf(sbuf[2], sbuf[3]));
  __syncthreads();
  return r;
}

// wave-local sum tree, identical lane order to block_sum256's intra-wave tree
__device__ __forceinline__ float wave_tree64(float v) {
#pragma unroll
  for (int o = 32; o > 0; o >>= 1) v += __shfl_down(v, o, 64);
  return v;
}

// exact sequential dot, bit-identical to round-1's k-ordered FMA accumulation
__device__ __forceinline__ float seq_dot(const float* __restrict__ xrow,
                                         const float* __restrict__ sr) {
  float acc = 0.f;
  for (int k = 0; k < V_N; k += 4) {
    float4 xv = *(const float4*)(xrow + k);
    acc = __builtin_fmaf(xv.x, sr[k + 0], acc);
    acc = __builtin_fmaf(xv.y, sr[k + 1], acc);
    acc = __builtin_fmaf(xv.z, sr[k + 2], acc);
    acc = __builtin_fmaf(xv.w, sr[k + 3], acc);
  }
  return acc;
}

// ---------------------------------------------------------------------------
// total_var pieces (also zeroes act_cnt)
// ---------------------------------------------------------------------------
__global__ __launch_bounds__(256) void rowvar_kernel(const float* __restrict__ y,
                                                     const float* __restrict__ mean_y,
                                                     float* __restrict__ rowvar,
                                                     int* __restrict__ act_cnt) {
  int b = blockIdx.x, t = threadIdx.x;
  __shared__ float sred[4];
  float4 yv = *(const float4*)(y + (size_t)b * V_N + t * 4);
  float4 mv = *(const float4*)(mean_y + t * 4);
  float dx = yv.x - mv.x, dy = yv.y - mv.y, dz = yv.z - mv.z, dw = yv.w - mv.w;
  float p = dx * dx + dy * dy + dz * dz + dw * dw;
  float s = block_sum256(p, sred);
  if (t == 0) { rowvar[b] = s; act_cnt[b] = 0; }
}

__global__ __launch_bounds__(256) void reduce_var_kernel(const float* __restrict__ rowvar,
                                                         float* __restrict__ totvar) {
  __shared__ float sred[4];
  int t = threadIdx.x;
  float p = 0.f;
#pragma unroll
  for (int i = 0; i < 4; i++) p += rowvar[t * 4 + i];
  float s = block_sum256(p, sred);
  if (t == 0) totvar[0] = s / (float)B_N;
}

// ---------------------------------------------------------------------------
// FAST PATH: xs -> bf16, R init (+ qv row scale)
// ---------------------------------------------------------------------------
__global__ __launch_bounds__(256) void xh_kernel(const float* __restrict__ xs,
                                                 u16* __restrict__ Xh) {
  int b = blockIdx.x, t = threadIdx.x;
  float4 v = *(const float4*)(xs + (size_t)b * V_N + t * 4);
  u16* o = Xh + (size_t)b * V_N + t * 4;
  o[0] = f2bf(v.x); o[1] = f2bf(v.y); o[2] = f2bf(v.z); o[3] = f2bf(v.w);
}

__global__ __launch_bounds__(256) void init_kernel(const float* __restrict__ x,
                                                   float* __restrict__ R,
                                                   u16* __restrict__ Rh,
                                                   float* __restrict__ rn2,
                                                   float* __restrict__ qv) {
  int b = blockIdx.x, t = threadIdx.x;
  __shared__ float sred[4];
  float4 v = *(const float4*)(x + (size_t)b * V_N + t * 4);
  *(float4*)(R + (size_t)b * V_N + t * 4) = v;
  u16* o = Rh + (size_t)b * V_N + t * 4;
  o[0] = f2bf(v.x); o[1] = f2bf(v.y); o[2] = f2bf(v.z); o[3] = f2bf(v.w);
  float p = v.x * v.x + v.y * v.y + v.z * v.z + v.w * v.w;
  float s = block_sum256(p, sred);
  if (t == 0) {
    rn2[b] = s;
    qv[b] = 250.0f / fmaxf(WINF * sqrtf(s), 1e-20f);
  }
}

// ---------------------------------------------------------------------------
// FAST PATH: bf16 MFMA GEMM, T3-minimum 2-phase double-buffered staging:
// STAGE(next) issued BEFORE ds_read+MFMA(cur); single __syncthreads per
// K-step (implicit vmcnt(0) drains prefetch + fences buffer swap).
// Epilogue: per-(row,tile) max + packed u8 quantized distance (unchanged).
// ---------------------------------------------------------------------------
__global__ __launch_bounds__(256) void gemm_scan_kernel(const u16* __restrict__ Rh,
                                                        const u16* __restrict__ Xh,
                                                        const float* __restrict__ qv,
                                                        u8* __restrict__ inner8,
                                                        float* __restrict__ pval) {
  __shared__ u16 As[2][128 * 32];
  __shared__ u16 Bs[2][128 * 32];
  __shared__ float srmax[128][2];
  const int tid = threadIdx.x;
  const int w = tid >> 6, l = tid & 63;
  const int bn = blockIdx.x, bm = blockIdx.y;
  const int wr = w >> 1, wc = w & 1;
  const int lr = l & 15, lg = l >> 4;

  f32x4 acc[4][4];
#pragma unroll
  for (int m = 0; m < 4; m++)
#pragma unroll
    for (int n = 0; n < 4; n++) acc[m][n] = (f32x4){0.f, 0.f, 0.f, 0.f};

  const u16* Ab = Rh + (size_t)bm * 128 * V_N;
  const u16* Bb = Xh + (size_t)bn * 128 * V_N;
  const int srow = w * 16 + (l >> 2);
  const int scol = (l & 3) * 8;

  // prologue: stage K-tile 0 into buffer 0
#pragma unroll
  for (int i = 0; i < 2; i++) {
    GLDS16(Ab + (size_t)(i * 64 + srow) * V_N + 0 + scol, &As[0][i * 2048 + w * 512]);
    GLDS16(Bb + (size_t)(i * 64 + srow) * V_N + 0 + scol, &Bs[0][i * 2048 + w * 512]);
  }
  __syncthreads();

  int cur = 0;
  for (int k0 = 0; k0 < V_N; k0 += 32) {
    int nxt = cur ^ 1;
    if (k0 + 32 < V_N) {
#pragma unroll
      for (int i = 0; i < 2; i++) {
        GLDS16(Ab + (size_t)(i * 64 + srow) * V_N + k0 + 32 + scol, &As[nxt][i * 2048 + w * 512]);
        GLDS16(Bb + (size_t)(i * 64 + srow) * V_N + k0 + 32 + scol, &Bs[nxt][i * 2048 + w * 512]);
      }
    }
    bf16x8 af[4], bfr[4];
#pragma unroll
    for (int m = 0; m < 4; m++) af[m] = *(const bf16x8*)&As[cur][(wr * 64 + m * 16 + lr) * 32 + lg * 8];
#pragma unroll
    for (int n = 0; n < 4; n++) bfr[n] = *(const bf16x8*)&Bs[cur][(wc * 64 + n * 16 + lr) * 32 + lg * 8];
#pragma unroll
    for (int m = 0; m < 4; m++)
#pragma unroll
      for (int n = 0; n < 4; n++)
        acc[m][n] = __builtin_amdgcn_mfma_f32_16x16x32_bf16(af[m], bfr[n], acc[m][n], 0, 0, 0);
    __syncthreads();   // drains vmcnt (next buffer staged) + all waves done with cur
    cur = nxt;
  }

  // phase 1: per-(row, 64-col-half) maxes into LDS
#pragma unroll
  for (int m = 0; m < 4; m++) {
#pragma unroll
    for (int j = 0; j < 4; j++) {
      float pm = acc[m][0][j];
#pragma unroll
      for (int n = 1; n < 4; n++) pm = fmaxf(pm, acc[m][n][j]);
#pragma unroll
      for (int mk = 1; mk < 16; mk <<= 1) pm = fmaxf(pm, __shfl_xor(pm, mk, 64));
      if (lr == 0) srmax[wr * 64 + m * 16 + lg * 4 + j][wc] = pm;
    }
  }
  __syncthreads();
  // pval write
  if (tid < 128) {
    float v = fmaxf(srmax[tid][0], srmax[tid][1]);
    pval[(size_t)(bm * 128 + tid) * NTILE + bn] = v;
  }
  // phase 2: packed u8 quantized distance (one u32 store per (m,j))
#pragma unroll
  for (int m = 0; m < 4; m++) {
#pragma unroll
    for (int j = 0; j < 4; j++) {
      int row = wr * 64 + m * 16 + lg * 4 + j;
      int gm = bm * 128 + row;
      float rmax = fmaxf(srmax[row][0], srmax[row][1]);
      float qinv = qv[gm];
      unsigned pack = 0;
#pragma unroll
      for (int n = 0; n < 4; n++) {
        float df = floorf((rmax - acc[m][n][j]) * qinv);
        unsigned u = df >= 254.f ? 254u : (unsigned)(int)df;
        pack |= u << (8 * n);
      }
      *(unsigned*)(inner8 + (size_t)gm * F_N + bn * 128 + wc * 64 + lr * 4) = pack;
    }
  }
}

// ---------------------------------------------------------------------------
// FAST PATH v13 (measured best): wide 2-barrier candidate collect; paired
// g-phase wave specialization; tiered overflow; fused csq/cr barrier.
// ---------------------------------------------------------------------------
__global__ __launch_bounds__(256, 4) void scan_update_kernel(const float* __restrict__ x,
                                                             const float* __restrict__ xs,
                                                             const u8* __restrict__ inner8,
                                                             const float* __restrict__ pval,
                                                             float* __restrict__ rn2,
                                                             float* __restrict__ qv,
                                                             int* __restrict__ act_ids,
                                                             float* __restrict__ act_w,
                                                             int* __restrict__ act_cnt,
                                                             float* __restrict__ R,
                                                             u16* __restrict__ Rh) {
  int b = blockIdx.x, t = threadIdx.x;
  const int lane = t & 63, wid = t >> 6;
  __shared__ float sr[V_N];
  __shared__ float spv[NTILE];
  __shared__ int   shot[NTILE];
  __shared__ int   snhot;
  __shared__ float sred[4];
  __shared__ float smax[4];
  __shared__ float scsqp[4], scrp[4];
  __shared__ int   scand[CAND2];
  __shared__ float scval[CAND2];
  __shared__ float sfv[256];
  __shared__ int   sfi[256];
  __shared__ int   scnt_c;
  __shared__ int   sbii;
  __shared__ float sg[NSEL + 2];
  __shared__ float sw[NSEL + 2];
  __shared__ int   sids[NSEL + 2];
  __shared__ int   ssel[NSEL + 2];
  __shared__ int   scnt, scnt0, sjnew;

  // ---- stage 1: residual row, x row, tile maxes, active set -> LDS
  float4 rv = *(const float4*)(R + (size_t)b * V_N + t * 4);
  float4 xrow = *(const float4*)(x + (size_t)b * V_N + t * 4);
  *(float4*)&sr[t * 4] = rv;
  if (t < NTILE) spv[t] = pval[(size_t)b * NTILE + t];
  if (t == 0) {
    scnt_c = 0; snhot = 0;
    int c0 = act_cnt[b]; scnt0 = c0;
    for (int j = 0; j < c0; j++) { sids[j] = act_ids[b * NSEL + j]; sw[j] = act_w[b * NSEL + j]; }
  }
  __syncthreads();

  // ---- stage 2: threshold from tile maxes
  float M = block_max256(spv[t & (NTILE - 1)], smax);
  float win = WINF * sqrtf(rn2[b]);
  float thr = M - win;
  float qinv = 250.0f / fmaxf(win, 1e-20f);   // same expression as qv producer

  // ---- stage 3: hot tiles + candidate collect from packed u8 filter
  if (t < NTILE && spv[t] >= thr) { int p = atomicAdd(&snhot, 1); shot[p] = t; }
  __syncthreads();
  int nh = snhot;
  const u8* irow8 = inner8 + (size_t)b * F_N;
  for (int h = 0; h < nh; h += 2) {
    int hh = h + (t >> 7);     // first 128 threads tile h, next 128 tile h+1
    if (hh < nh) {
      int tt = shot[hh];
      int lim = (int)floorf((spv[tt] - thr) * qinv);
      int p = t & 127;
      int u8v = irow8[tt * 128 + p];
      if (u8v <= lim) {
        int col = (p & 64) + (p & 3) * 16 + ((p >> 2) & 15);   // un-permute
        int q = atomicAdd(&scnt_c, 1); if (q < CAND2) scand[q] = tt * 128 + col;
      }
    }
  }
  __syncthreads();
  int total = scnt_c;
  int cnt0 = scnt0;

  // ---- stage 4: CONCURRENT {waves 1-3: paired g for active atoms} |
  //                          {wave 0: exact rescore}
  if (wid >= 1) {
#pragma unroll
    for (int bb = 0; bb < 3; bb++) {
      int j0 = (wid - 1) + 3 * (2 * bb);
      int j1 = (wid - 1) + 3 * (2 * bb + 1);
      bool v0 = (j0 < cnt0) && (sw[j0] != 0.f);   // wave-uniform (LDS)
      bool v1 = (j1 < cnt0) && (sw[j1] != 0.f);
      const float* xr0 = xs + (size_t)sids[v0 ? j0 : 0] * V_N;
      const float* xr1 = xs + (size_t)sids[v1 ? j1 : 0] * V_N;
      float4 a0[4], a1[4];
#pragma unroll
      for (int vw = 0; vw < 4; vw++) {
        int vt = vw * 64 + lane;
        if (v0) a0[vw] = *(const float4*)(xr0 + vt * 4);
        if (v1) a1[vw] = *(const float4*)(xr1 + vt * 4);
      }
      if (v0) {
        float part[4];
#pragma unroll
        for (int vw = 0; vw < 4; vw++) {
          int vt = vw * 64 + lane;
          float4 rl4 = *(const float4*)&sr[vt * 4];
          float p = a0[vw].x * rl4.x + a0[vw].y * rl4.y + a0[vw].z * rl4.z + a0[vw].w * rl4.w;
          part[vw] = wave_tree64(p);
        }
        if (lane == 0) sg[j0] = part[0] + part[1] + part[2] + part[3];
      }
      if (v1) {
        float part[4];
#pragma unroll
        for (int vw = 0; vw < 4; vw++) {
          int vt = vw * 64 + lane;
          float4 rl4 = *(const float4*)&sr[vt * 4];
          float p = a1[vw].x * rl4.x + a1[vw].y * rl4.y + a1[vw].z * rl4.z + a1[vw].w * rl4.w;
          part[vw] = wave_tree64(p);
        }
        if (lane == 0) sg[j1] = part[0] + part[1] + part[2] + part[3];
      }
    }
  } else if (total <= CANDMAX) {
    int nc = total;
    if (nc == 1) {
      if (lane == 0) sbii = scand[0];
    } else {
      if (lane < nc) scval[lane] = seq_dot(xs + (size_t)scand[lane] * V_N, sr);
      if (lane == 0) {
        float bv = scval[0]; int bi = scand[0];
        for (int c = 1; c < nc; c++) {
          float v = scval[c]; int id = scand[c];
          if (v > bv || (v == bv && id < bi)) { bv = v; bi = id; }
        }
        sbii = bi;
      }
    }
  }
  __syncthreads();

  if (total > CANDMAX && total <= CAND2) {
    // tier 2: all-256-thread rescore of collected candidates (cheap)
    if (t < total) scval[t] = seq_dot(xs + (size_t)scand[t] * V_N, sr);
    __syncthreads();
    if (t == 0) {
      float bv = scval[0]; int bi = scand[0];
      for (int c = 1; c < total; c++) {
        float v = scval[c]; int id = scand[c];
        if (v > bv || (v == bv && id < bi)) { bv = v; bi = id; }
      }
      sbii = bi;
    }
    __syncthreads();
  } else if (total > CAND2) {
    // tier 3: FULL exact fallback (same arithmetic as round-1 scan order)
    float bv = -1e30f; int bi = 0x7fffffff;
    for (int f = t; f < F_N; f += 256) {
      float acc = seq_dot(xs + (size_t)f * V_N, sr);
      if (acc > bv) { bv = acc; bi = f; }
    }
    sfv[t] = bv; sfi[t] = bi;
    __syncthreads();
    if (t == 0) {
      float bbv = sfv[0]; int bbi = sfi[0];
      for (int c = 1; c < 256; c++) {
        float v = sfv[c]; int id = sfi[c];
        if (v > bbv || (v == bbv && id < bbi)) { bbv = v; bbi = id; }
      }
      sbii = bbi;
    }
    __syncthreads();
  }

  // ---- stage 5: merge argmax into active set (t==0)
  if (t == 0) {
    int bi = sbii;
    int cnt = cnt0;
    int pos = -1;
    for (int j = 0; j < cnt; j++) if (sids[j] == bi) pos = j;
    if (pos < 0) { pos = cnt; sids[cnt] = bi; sw[cnt] = 0.f; cnt++; }
    for (int j = 0; j < cnt; j++) ssel[j] = (sw[j] != 0.f) || (j == pos) ? 1 : 0;
    for (int j = 0; j < cnt; j++) if (!ssel[j]) sg[j] = 0.f;
    sjnew = (sw[pos] == 0.f) ? pos : -1;
    scnt = cnt;
  }
  __syncthreads();
  int cnt = scnt;

  // ---- stage 6: g for newly-selected zero-weight atom (wave 0)
  int jnew = sjnew;
  if (jnew >= 0 && wid == 0) {
    const float* xr0 = xs + (size_t)sids[jnew] * V_N;
    float part[4];
#pragma unroll
    for (int vw = 0; vw < 4; vw++) {
      int vt = vw * 64 + lane;
      float4 xvv = *(const float4*)(xr0 + vt * 4);
      float4 rl4 = *(const float4*)&sr[vt * 4];
      float p = xvv.x * rl4.x + xvv.y * rl4.y + xvv.z * rl4.z + xvv.w * rl4.w;
      part[vw] = wave_tree64(p);
    }
    if (lane == 0) sg[jnew] = part[0] + part[1] + part[2] + part[3];
  }
  __syncthreads();

  // ---- stage 6.5: batched register prefetch of all selected rows
  float4 rl = *(const float4*)&sr[t * 4];
  float4 xv[NSEL + 1];
#pragma unroll
  for (int j = 0; j < NSEL + 1; j++) {
    int jj = j < cnt ? j : 0;
    xv[j] = *(const float4*)(xs + (size_t)sids[jj] * V_N + t * 4);
  }

  // ---- stage 7: c = sum_j g_j D_j (from registers, ascending j)
  float4 cv = {0.f, 0.f, 0.f, 0.f};
#pragma unroll
  for (int j = 0; j < NSEL + 1; j++) {
    if (j < cnt) {
      if (ssel[j]) {   // uniform (LDS)
        float g = sg[j];
        cv.x += g * xv[j].x; cv.y += g * xv[j].y; cv.z += g * xv[j].z; cv.w += g * xv[j].w;
      }
    }
  }
  float pcsq = cv.x * cv.x + cv.y * cv.y + cv.z * cv.z + cv.w * cv.w;
  float pcr  = cv.x * rl.x + cv.y * rl.y + cv.z * rl.z + cv.w * rl.w;
  {
    // fused csq/cr: wave trees + single barrier + same 4-term L2R combine
    float s1 = wave_tree64(pcsq);
    float s2 = wave_tree64(pcr);
    if (lane == 0) { scsqp[wid] = s1; scrp[wid] = s2; }
  }
  __syncthreads();

  if (t == 0) {
    float csq = scsqp[0] + scsqp[1] + scsqp[2] + scsqp[3];
    float cr  = scrp[0] + scrp[1] + scrp[2] + scrp[3];
    float step = cr / fmaxf(csq, EPSV);
    for (int j = 0; j < cnt; j++)
      if (ssel[j]) sw[j] = fmaxf(sw[j] + step * sg[j], 0.f);
    for (int j = 0; j < cnt; j++) {
      act_ids[b * NSEL + j] = sids[j];
      act_w[b * NSEL + j] = sw[j];
    }
    act_cnt[b] = cnt;
  }
  __syncthreads();

  // ---- stage 8: new residual from cached rows (ascending j); R/Rh/rn2/qv
  float4 r = xrow;
#pragma unroll
  for (int j = 0; j < NSEL + 1; j++) {
    if (j < cnt) {
      float wv = sw[j];
      if (wv != 0.f) {   // uniform (LDS); w!=0 => selected => xv[j] valid
        r.x -= wv * xv[j].x; r.y -= wv * xv[j].y; r.z -= wv * xv[j].z; r.w -= wv * xv[j].w;
      }
    }
  }
  *(float4*)(R + (size_t)b * V_N + t * 4) = r;
  u16* o = Rh + (size_t)b * V_N + t * 4;
  o[0] = f2bf(r.x); o[1] = f2bf(r.y); o[2] = f2bf(r.z); o[3] = f2bf(r.w);
  float p2 = r.x * r.x + r.y * r.y + r.z * r.z + r.w * r.w;
  float s2 = block_sum256(p2, sred);
  if (t == 0) {
    rn2[b] = s2;
    qv[b] = 250.0f / fmaxf(WINF * sqrtf(s2), 1e-20f);
  }
}

// ---------------------------------------------------------------------------
// FALLBACK PATH (round-1 fp32 pipeline, used only if ws_size is too small)
// ---------------------------------------------------------------------------
__global__ __launch_bounds__(256) void residual_kernel(const float* __restrict__ x,
                                                       const float* __restrict__ xs,
                                                       const int* __restrict__ act_ids,
                                                       const float* __restrict__ act_w,
                                                       const int* __restrict__ act_cnt,
                                                       float* __restrict__ R) {
  int b = blockIdx.x, t = threadIdx.x;
  float4 r = *(const float4*)(x + (size_t)b * V_N + t * 4);
  int cnt = act_cnt[b];
  for (int j = 0; j < cnt; j++) {
    float w = act_w[b * NSEL + j];
    if (w != 0.f) {
      const float* xr = xs + (size_t)act_ids[b * NSEL + j] * V_N;
      float4 xv = *(const float4*)(xr + t * 4);
      r.x -= w * xv.x; r.y -= w * xv.y; r.z -= w * xv.z; r.w -= w * xv.w;
    }
  }
  *(float4*)(R + (size_t)b * V_N + t * 4) = r;
}

__global__ __launch_bounds__(256) void gemm_argmax_kernel(const float* __restrict__ R,
                                                          const float* __restrict__ xs,
                                                          float* __restrict__ pval,
                                                          int* __restrict__ pidx) {
  __shared__ float sA[BK * 68];
  __shared__ float sB[BK * 132];
  __shared__ float sMv[64 * 33];
  __shared__ int   sMi[64 * 33];

  int tid = threadIdx.x;
  int bn = blockIdx.x, bm = blockIdx.y;
  float acc[8][4];
#pragma unroll
  for (int i = 0; i < 8; i++)
#pragma unroll
    for (int j = 0; j < 4; j++) acc[i][j] = 0.f;

  int r0 = (tid >> 5) << 3;
  int n0 = (tid & 31) << 2;
  const float* Rbase = R + (size_t)(bm * BM) * V_N;
  const float* Xbase = xs + (size_t)(bn * BN) * V_N;

  for (int k0 = 0; k0 < V_N; k0 += BK) {
    {
      int m = tid >> 2, kf = (tid & 3) * 4;
      float4 v = *(const float4*)(Rbase + (size_t)m * V_N + k0 + kf);
      sA[(kf + 0) * 68 + m] = v.x; sA[(kf + 1) * 68 + m] = v.y;
      sA[(kf + 2) * 68 + m] = v.z; sA[(kf + 3) * 68 + m] = v.w;
      float4 v2 = *(const float4*)(Rbase + (size_t)m * V_N + k0 + kf + 16);
      sA[(kf + 16) * 68 + m] = v2.x; sA[(kf + 17) * 68 + m] = v2.y;
      sA[(kf + 18) * 68 + m] = v2.z; sA[(kf + 19) * 68 + m] = v2.w;
    }
    {
      int nn = tid >> 3, kf = (tid & 7) * 4;
#pragma unroll
      for (int i = 0; i < 4; i++) {
        int n = nn + i * 32;
        float4 v = *(const float4*)(Xbase + (size_t)n * V_N + k0 + kf);
        sB[(kf + 0) * 132 + n] = v.x; sB[(kf + 1) * 132 + n] = v.y;
        sB[(kf + 2) * 132 + n] = v.z; sB[(kf + 3) * 132 + n] = v.w;
      }
    }
    __syncthreads();
#pragma unroll
    for (int k = 0; k < BK; k++) {
      float4 aL = *(float4*)&sA[k * 68 + r0];
      float4 aH = *(float4*)&sA[k * 68 + r0 + 4];
      float4 bv = *(float4*)&sB[k * 132 + n0];
      float a[8] = {aL.x, aL.y, aL.z, aL.w, aH.x, aH.y, aH.z, aH.w};
      float bb[4] = {bv.x, bv.y, bv.z, bv.w};
#pragma unroll
      for (int i = 0; i < 8; i++)
#pragma unroll
        for (int j = 0; j < 4; j++) acc[i][j] += a[i] * bb[j];
    }
    __syncthreads();
  }

#pragma unroll
  for (int i = 0; i < 8; i++) {
    float bvv = acc[i][0]; int bj = 0;
#pragma unroll
    for (int j = 1; j < 4; j++)
      if (acc[i][j] > bvv) { bvv = acc[i][j]; bj = j; }
    sMv[(r0 + i) * 33 + (tid & 31)] = bvv;
    sMi[(r0 + i) * 33 + (tid & 31)] = bn * BN + n0 + bj;
  }
  __syncthreads();
  if (tid < 64) {
    float bvv = sMv[tid * 33]; int bi = sMi[tid * 33];
    for (int c = 1; c < 32; c++) {
      float v = sMv[tid * 33 + c];
      if (v > bvv) { bvv = v; bi = sMi[tid * 33 + c]; }
    }
    pval[(size_t)(bm * BM + tid) * NBN + bn] = bvv;
    pidx[(size_t)(bm * BM + tid) * NBN + bn] = bi;
  }
}

__global__ __launch_bounds__(256) void combine_update_kernel(const float* __restrict__ R,
                                                             const float* __restrict__ xs,
                                                             const float* __restrict__ pval,
                                                             const int* __restrict__ pidx,
                                                             int* __restrict__ act_ids,
                                                             float* __restrict__ act_w,
                                                             int* __restrict__ act_cnt) {
  int b = blockIdx.x, t = threadIdx.x;
  __shared__ float sr[V_N];
  __shared__ float sred[4];
  __shared__ float sg[NSEL + 1];
  __shared__ float sw[NSEL + 1];
  __shared__ int   sids[NSEL + 1];
  __shared__ int   ssel[NSEL + 1];
  __shared__ int   scnt;

  float4 rv = *(const float4*)(R + (size_t)b * V_N + t * 4);
  *(float4*)&sr[t * 4] = rv;

  if (t == 0) {
    const float* pv = pval + (size_t)b * NBN;
    const int* pi = pidx + (size_t)b * NBN;
    float bv = pv[0]; int bi = pi[0];
    for (int c = 1; c < NBN; c++) {
      float v = pv[c];
      if (v > bv) { bv = v; bi = pi[c]; }
    }
    int cnt = act_cnt[b];
    for (int j = 0; j < cnt; j++) { sids[j] = act_ids[b * NSEL + j]; sw[j] = act_w[b * NSEL + j]; }
    int pos = -1;
    for (int j = 0; j < cnt; j++) if (sids[j] == bi) pos = j;
    if (pos < 0) { pos = cnt; sids[cnt] = bi; sw[cnt] = 0.f; cnt++; }
    for (int j = 0; j < cnt; j++) ssel[j] = (sw[j] != 0.f) || (j == pos) ? 1 : 0;
    scnt = cnt;
  }
  __syncthreads();
  int cnt = scnt;

  for (int j = 0; j < cnt; j++) {
    if (!ssel[j]) { if (t == 0) sg[j] = 0.f; continue; }
    const float* xr = xs + (size_t)sids[j] * V_N;
    float4 xv = *(const float4*)(xr + t * 4);
    float4 rl = *(const float4*)&sr[t * 4];
    float p = xv.x * rl.x + xv.y * rl.y + xv.z * rl.z + xv.w * rl.w;
    float s = block_sum256(p, sred);
    if (t == 0) sg[j] = s;
  }
  __syncthreads();

  float4 cv = {0.f, 0.f, 0.f, 0.f};
  for (int j = 0; j < cnt; j++) {
    if (ssel[j]) {
      float g = sg[j];
      const float* xr = xs + (size_t)sids[j] * V_N;
      float4 xv = *(const float4*)(xr + t * 4);
      cv.x += g * xv.x; cv.y += g * xv.y; cv.z += g * xv.z; cv.w += g * xv.w;
    }
  }
  float4 rl = *(const float4*)&sr[t * 4];
  float pcsq = cv.x * cv.x + cv.y * cv.y + cv.z * cv.z + cv.w * cv.w;
  float pcr  = cv.x * rl.x + cv.y * rl.y + cv.z * rl.z + cv.w * rl.w;
  float csq = block_sum256(pcsq, sred);
  float cr  = block_sum256(pcr, sred);

  if (t == 0) {
    float step = cr / fmaxf(csq, EPSV);
    for (int j = 0; j < cnt; j++)
      if (ssel[j]) sw[j] = fmaxf(sw[j] + step * sg[j], 0.f);
    for (int j = 0; j < cnt; j++) {
      act_ids[b * NSEL + j] = sids[j];
      act_w[b * NSEL + j] = sw[j];
    }
    act_cnt[b] = cnt;
  }
}

// ---------------------------------------------------------------------------
// top-k + decode (shared by both paths)
// ---------------------------------------------------------------------------
__global__ __launch_bounds__(256) void topk_kernel(const int* __restrict__ act_ids,
                                                   const float* __restrict__ act_w,
                                                   const int* __restrict__ act_cnt,
                                                   float* __restrict__ out_w,
                                                   float* __restrict__ out_i) {
  int b = blockIdx.x * blockDim.x + threadIdx.x;
  if (b >= B_N) return;
  int cnt = act_cnt[b];
  int ids[NSEL]; float w[NSEL]; int m = 0;
  for (int j = 0; j < cnt; j++) {
    float wv = act_w[b * NSEL + j];
    if (wv > 0.f) { ids[m] = act_ids[b * NSEL + j]; w[m] = wv; m++; }
  }
  for (int i = 1; i < m; i++) {
    float wv = w[i]; int id = ids[i]; int j = i - 1;
    while (j >= 0 && (w[j] < wv || (w[j] == wv && ids[j] > id))) {
      w[j + 1] = w[j]; ids[j + 1] = ids[j]; j--;
    }
    w[j + 1] = wv; ids[j + 1] = id;
  }
  int nf = 0;
  for (int s = m; s < NSEL; s++) {
    for (;;) {
      bool used = false;
      for (int j = 0; j < m; j++) if (ids[j] == nf) used = true;
      if (!used) break;
      nf++;
    }
    ids[s] = nf; w[s] = 0.f; nf++;
  }
  for (int s = 0; s < NSEL; s++) {
    out_w[b * NSEL + s] = w[s];
    out_i[b * NSEL + s] = (float)ids[s];
  }
}

__global__ __launch_bounds__(256) void decode_kernel(const float* __restrict__ y,
                                                     const float* __restrict__ xs,
                                                     const float* __restrict__ ys,
                                                     const float* __restrict__ out_w,
                                                     const float* __restrict__ out_i,
                                                     const float* __restrict__ totvar,
                                                     float* __restrict__ x_rec,
                                                     float* __restrict__ y_rec,
                                                     float* __restrict__ losses) {
  int b = blockIdx.x, t = threadIdx.x;
  __shared__ float swv[NSEL];
  __shared__ int sid[NSEL];
  __shared__ float sred[4];
  if (t < NSEL) { swv[t] = out_w[b * NSEL + t]; sid[t] = (int)out_i[b * NSEL + t]; }
  __syncthreads();
  float4 xr = {0.f, 0.f, 0.f, 0.f}, yr = {0.f, 0.f, 0.f, 0.f};
  for (int s = 0; s < NSEL; s++) {
    float wv = swv[s];
    if (wv != 0.f) {
      const float* xrow = xs + (size_t)sid[s] * V_N;
      const float* yrow = ys + (size_t)sid[s] * V_N;
      float4 a = *(const float4*)(xrow + t * 4);
      float4 c = *(const float4*)(yrow + t * 4);
      xr.x += wv * a.x; xr.y += wv * a.y; xr.z += wv * a.z; xr.w += wv * a.w;
      yr.x += wv * c.x; yr.y += wv * c.y; yr.z += wv * c.z; yr.w += wv * c.w;
    }
  }
  *(float4*)(x_rec + (size_t)b * V_N + t * 4) = xr;
  *(float4*)(y_rec + (size_t)b * V_N + t * 4) = yr;
  float4 yv = *(const float4*)(y + (size_t)b * V_N + t * 4);
  float dx = yv.x - yr.x, dy = yv.y - yr.y, dz = yv.z - yr.z, dw = yv.w - yr.w;
  float p = dx * dx + dy * dy + dz * dz + dw * dw;
  float l2 = block_sum256(p, sred);
  if (t == 0) losses[b] = l2 / totvar[0];
}

// ---------------------------------------------------------------------------
// launch
// ---------------------------------------------------------------------------
extern "C" void kernel_launch(void* const* d_in, const int* in_sizes, int n_in,
                              void* d_out, int out_size, void* d_ws, size_t ws_size,
                              hipStream_t stream) {
  const float* x      = (const float*)d_in[0];
  const float* y      = (const float*)d_in[1];
  const float* xs     = (const float*)d_in[2];
  const float* ys     = (const float*)d_in[3];
  const float* mean_y = (const float*)d_in[4];
  (void)in_sizes; (void)n_in; (void)out_size;

  float* out    = (float*)d_out;
  float* out_w  = out;
  float* out_i  = out + 16384;
  float* out_xr = out + 32768;
  float* out_yr = out + 32768 + 1048576;
  float* out_ls = out + 32768 + 2097152;

  float* ws = (float*)d_ws;

  const size_t FAST_NEED = (size_t)14258177 * 4;

  if (ws_size >= FAST_NEED) {
    float* R      = ws;
    u8*    inner8 = (u8*)(ws + 1048576);      // 8.39 MB
    u16*   Rh     = (u16*)(ws + 5242880);
    u16*   Xh     = (u16*)(ws + 5767168);
    float* rn2    = ws + 9961472;
    int*   aid    = (int*)(ws + 9962496);
    float* aw     = ws + 9978880;
    int*   acn    = (int*)(ws + 9995264);
    float* rv     = ws + 9996288;
    float* tv     = ws + 9997312;
    float* pval   = ws + 14191617;
    float* qv     = ws + 14257153;

    rowvar_kernel<<<B_N, 256, 0, stream>>>(y, mean_y, rv, acn);
    reduce_var_kernel<<<1, 256, 0, stream>>>(rv, tv);
    xh_kernel<<<F_N, 256, 0, stream>>>(xs, Xh);
    init_kernel<<<B_N, 256, 0, stream>>>(x, R, Rh, rn2, qv);

    for (int it = 0; it < NITER; it++) {
      gemm_scan_kernel<<<dim3(F_N / 128, B_N / 128), 256, 0, stream>>>(Rh, Xh, qv, inner8, pval);
      scan_update_kernel<<<B_N, 256, 0, stream>>>(x, xs, inner8, pval, rn2, qv, aid, aw, acn, R, Rh);
    }

    topk_kernel<<<(B_N + 255) / 256, 256, 0, stream>>>(aid, aw, acn, out_w, out_i);
    decode_kernel<<<B_N, 256, 0, stream>>>(y, xs, ys, out_w, out_i, tv, out_xr, out_yr, out_ls);
  } else {
    float* R    = ws;
    float* pval = ws + 1048576;
    int*   pidx = (int*)(ws + 1114112);
    int*   aid  = (int*)(ws + 1179648);
    float* aw   = ws + 1196032;
    int*   acn  = (int*)(ws + 1212416);
    float* rv   = ws + 1213440;
    float* tv   = ws + 1214464;

    rowvar_kernel<<<B_N, 256, 0, stream>>>(y, mean_y, rv, acn);
    reduce_var_kernel<<<1, 256, 0, stream>>>(rv, tv);

    for (int it = 0; it < NITER; it++) {
      residual_kernel<<<B_N, 256, 0, stream>>>(x, xs, aid, aw, acn, R);
      gemm_argmax_kernel<<<dim3(NBN, B_N / BM), 256, 0, stream>>>(R, xs, pval, pidx);
      combine_update_kernel<<<B_N, 256, 0, stream>>>(R, xs, pval, pidx, aid, aw, acn);
    }

    topk_kernel<<<(B_N + 255) / 256, 256, 0, stream>>>(aid, aw, acn, out_w, out_i);
    decode_kernel<<<B_N, 256, 0, stream>>>(y, xs, ys, out_w, out_i, tv, out_xr, out_yr, out_ls);
  }
}